// Round 6
// baseline (1252.097 us; speedup 1.0000x reference)
//
#include <hip/hip_runtime.h>
#include <math.h>

// GRU_32564442038643 — round 6.
//  R5 post-mortem: VGPR_Count=124 @ 2 waves/SIMD -> ~15/48 weight frags still demoted
//  to per-step L2 reloads; SQ_LDS_BANK_CONFLICT 4.2M = 512 cyc/step of *write-side*
//  (ds_write_b16) conflicts. Fixes: (1) pin weight frags to AGPRs via asm "+a"
//  (MFMA B reads AGPR directly on gfx950); (2) XOR-swizzle Hb/RHb columns by
//  (row>>2)*8 -> write banks near-disjoint, reads stay aligned b128 (free);
//  (3) xgemm at 512 thr / 2 waves/SIMD with the same pin.

#define BATCH  256
#define SEQ    512
#define INPUT  256
#define HIDDEN 256
#define DTOT   512
#define NTC    48
#define NT_O   16
#define LOG2E  1.44269504088896f

typedef float          f32x4 __attribute__((ext_vector_type(4)));
typedef short          s16x8 __attribute__((ext_vector_type(8)));
typedef unsigned short u16x8 __attribute__((ext_vector_type(8)));
typedef unsigned int   u32x2 __attribute__((ext_vector_type(2)));

// ws layout (bytes)
#define WH_OFF   0u
#define WX_OFF   393216u
#define WO_OFF   786432u
#define X_OFF    917504u
#define WS_NEED     (917504ull + 201326592ull)
#define WS_NEED_OLD 786432ull

// Force a fragment into the AGPR file (one-time v_accvgpr_write at the pin point).
#define PIN_A(v) asm volatile("" : "+a"(v))

__device__ __forceinline__ unsigned short f2bf(float f) {        // RNE
    unsigned int u = __float_as_uint(f);
    u += 0x7FFFu + ((u >> 16) & 1u);
    return (unsigned short)(u >> 16);
}
__device__ __forceinline__ unsigned short f2bf_fast(float f) {
    return (unsigned short)((__float_as_uint(f) + 0x8000u) >> 16);
}
__device__ __forceinline__ float bf2f(unsigned short u) {
    return __uint_as_float(((unsigned int)u) << 16);
}
__device__ __forceinline__ f32x4 cvt4(u32x2 u) {
    f32x4 a;
    a[0] = __uint_as_float(u[0] << 16);
    a[1] = __uint_as_float(u[0] & 0xffff0000u);
    a[2] = __uint_as_float(u[1] << 16);
    a[3] = __uint_as_float(u[1] & 0xffff0000u);
    return a;
}
__device__ __forceinline__ unsigned int pk2bf(float a, float b) {
    return ((__float_as_uint(a) + 0x8000u) >> 16) |
           ((__float_as_uint(b) + 0x8000u) & 0xFFFF0000u);
}
#if __has_builtin(__builtin_amdgcn_exp2f)
#define EXP2F(x) __builtin_amdgcn_exp2f(x)
#else
#define EXP2F(x) exp2f(x)
#endif
#if __has_builtin(__builtin_amdgcn_rcpf)
#define RCPF(x) __builtin_amdgcn_rcpf(x)
#else
#define RCPF(x) (1.0f / (x))
#endif

__device__ __forceinline__ void async_ld16(const void* g, void* l) {
    __builtin_amdgcn_global_load_lds(
        (const __attribute__((address_space(1))) unsigned int*)g,
        (__attribute__((address_space(3))) unsigned int*)l, 16, 0, 0);
}

__device__ __forceinline__ void ntc_decode(int ntc, int& gate, int& colbase) {
    int w = ntc / 6, s = ntc - 6 * w;
    gate = s >> 1;
    colbase = (2 * w + (s & 1)) * 16;
}

// ---------------- weight packing (unchanged layout from R5) ----------------
__global__ __launch_bounds__(256) void pack_weights_k(
    const float* __restrict__ Wr, const float* __restrict__ Wz,
    const float* __restrict__ Wh, const float* __restrict__ Wo,
    unsigned short* __restrict__ ws)
{
    int tid = blockIdx.x * 256 + threadIdx.x;
    int tile = tid >> 6;
    int l = tid & 63, quad = l >> 4, lan = l & 15;
    u16x8 v;
    unsigned short* dst;
    if (tile < 768) {
        int isH = tile < 384;
        int t2 = isH ? tile : tile - 384;       // = ntc*8 + kt
        int ntc = t2 >> 3, kt = t2 & 7;
        int gate, colbase;
        ntc_decode(ntc, gate, colbase);
        const float* W = gate == 0 ? Wr : (gate == 1 ? Wz : Wh);
        float scale = (gate == 2) ? 2.f * LOG2E : LOG2E;
        int col = colbase + lan;
        int kbase = (isH ? 256 : 0) + kt * 32 + quad * 8;
        #pragma unroll
        for (int j = 0; j < 8; ++j) v[j] = f2bf(W[(kbase + j) * 256 + col] * scale);
        dst = (unsigned short*)((char*)ws + (isH ? WH_OFF : WX_OFF)) + (size_t)(t2 * 64 + l) * 8;
    } else {
        int t2 = tile - 768;                    // = kt*16 + nt_o
        int kt = t2 / NT_O, nt = t2 % NT_O;
        int col = nt * 16 + lan;
        int kbase = kt * 32 + quad * 8;
        #pragma unroll
        for (int j = 0; j < 8; ++j) v[j] = f2bf(Wo[(kbase + j) * 256 + col]);
        dst = (unsigned short*)((char*)ws + WO_OFF) + (size_t)(t2 * 64 + l) * 8;
    }
    *(u16x8*)dst = v;
}

// ---------------- X precompute: 256 WGs x 512 thr (2 waves/SIMD) ----------------
// Wave w (0..7) owns ntc 6w..6w+5 (48 frags = 192 regs, AGPR-pinned).
__global__ __launch_bounds__(512, 2) void xgemm_k(
    const float* __restrict__ x,
    const float* __restrict__ br, const float* __restrict__ bz, const float* __restrict__ bh,
    unsigned short* __restrict__ ws)
{
    __shared__ __align__(16) float Xf[2][16][264];
    const int th = threadIdx.x, wave = th >> 6, l = th & 63, quad = l >> 4, lan = l & 15;
    const s16x8* WX = (const s16x8*)((char*)ws + WX_OFF);
    s16x8 wx[6][8];
    #pragma unroll
    for (int fi = 0; fi < 6; ++fi)
        #pragma unroll
        for (int kt = 0; kt < 8; ++kt) {
            wx[fi][kt] = WX[(((size_t)(6 * wave + fi)) * 8 + kt) * 64 + l];
            PIN_A(wx[fi][kt]);
        }
    float bias[6];
    #pragma unroll
    for (int fi = 0; fi < 6; ++fi) {
        int gate, colbase;
        ntc_decode(6 * wave + fi, gate, colbase);
        const float* bb = gate == 0 ? br : (gate == 1 ? bz : bh);
        bias[fi] = bb[colbase + lan] * (gate == 2 ? 2.f * LOG2E : LOG2E);
    }
    u32x2* Xout = (u32x2*)((char*)ws + X_OFF);

    {   // prime unit 0 -> buf 0 (wave stages rows 2w, 2w+1)
        int unit = blockIdx.x * 32, t = unit >> 4, gg = unit & 15;
        #pragma unroll
        for (int rr = 0; rr < 2; ++rr) {
            int row = 2 * wave + rr;
            const float* src = x + (((size_t)(gg * 16 + row)) * SEQ + t) * INPUT + l * 4;
            async_ld16(src, &Xf[0][row][0]);
        }
    }
    for (int uu = 0; uu < 32; ++uu) {
        __syncthreads();                         // drains this buf's staging
        if (uu + 1 < 32) {
            int unit = blockIdx.x * 32 + uu + 1, t = unit >> 4, gg = unit & 15;
            int nb = (uu + 1) & 1;
            #pragma unroll
            for (int rr = 0; rr < 2; ++rr) {
                int row = 2 * wave + rr;
                const float* src = x + (((size_t)(gg * 16 + row)) * SEQ + t) * INPUT + l * 4;
                async_ld16(src, &Xf[nb][row][0]);
            }
        }
        int buf = uu & 1;
        f32x4 acc[6];
        #pragma unroll
        for (int fi = 0; fi < 6; ++fi) { acc[fi][0] = bias[fi]; acc[fi][1] = bias[fi]; acc[fi][2] = bias[fi]; acc[fi][3] = bias[fi]; }
        #pragma unroll
        for (int kt = 0; kt < 8; ++kt) {
            f32x4 a0 = *(const f32x4*)&Xf[buf][lan][kt * 32 + quad * 8];
            f32x4 a1 = *(const f32x4*)&Xf[buf][lan][kt * 32 + quad * 8 + 4];
            u16x8 ap;
            ap[0] = f2bf_fast(a0[0]); ap[1] = f2bf_fast(a0[1]); ap[2] = f2bf_fast(a0[2]); ap[3] = f2bf_fast(a0[3]);
            ap[4] = f2bf_fast(a1[0]); ap[5] = f2bf_fast(a1[1]); ap[6] = f2bf_fast(a1[2]); ap[7] = f2bf_fast(a1[3]);
            s16x8 a = (s16x8)ap;
            #pragma unroll
            for (int fi = 0; fi < 6; ++fi)
                acc[fi] = __builtin_amdgcn_mfma_f32_16x16x32_bf16(a, wx[fi][kt], acc[fi], 0, 0, 0);
        }
        size_t unit = (size_t)blockIdx.x * 32 + uu;
        #pragma unroll
        for (int fi = 0; fi < 6; ++fi) {
            u32x2 p;
            p[0] = pk2bf(acc[fi][0], acc[fi][1]);
            p[1] = pk2bf(acc[fi][2], acc[fi][3]);
            Xout[(unit * NTC + 6 * wave + fi) * 64 + l] = p;
        }
    }
}

// ---------------- recurrence: 16 WGs x 512 thr (2 waves/SIMD) ----------------
// Wave w owns ntc 6w..6w+5 (r,z,cand of cols 32w..32w+31): 48 frags AGPR-pinned.
// Hb/RHb columns XOR-swizzled by (row>>2)*8 to kill write-side bank conflicts.
// Dynamic LDS: Hb 8448 | RHb 8448 | Xring 49152 = 66048 B.
__global__ __launch_bounds__(512, 2) void gru_rec_k(
    const float* __restrict__ bo,
    unsigned short* __restrict__ ws,
    float* __restrict__ out)
{
    extern __shared__ __align__(16) char smem[];
    unsigned short (*Hb)[264]  = (unsigned short (*)[264])smem;
    unsigned short (*RHb)[264] = (unsigned short (*)[264])(smem + 8448);
    char* Xr = smem + 16896;                       // [2][8 waves][3072]

    const int th = threadIdx.x, wave = th >> 6, l = th & 63, quad = l >> 4, lan = l & 15;
    const int b = blockIdx.x;
    // A-frag read offset with swizzle: logical quad -> quad ^ (lan>>2)
    const int qx8 = ((quad ^ (lan >> 2)) << 3);    // in shorts
    // write columns with swizzle: col ^ (quad*8)   (row>>2 == quad for rows quad*4+r)
    int colw[2];
    #pragma unroll
    for (int i = 0; i < 2; ++i) colw[i] = (((2 * wave + i) * 16 + lan) ^ (quad << 3));

    const s16x8* WH = (const s16x8*)((char*)ws + WH_OFF);
    s16x8 wfr[2][8], wfz[2][8], wfc[2][8];         // 48 frags -> AGPR
    #pragma unroll
    for (int i = 0; i < 2; ++i)
        #pragma unroll
        for (int kt = 0; kt < 8; ++kt) {
            wfr[i][kt] = WH[((6 * wave + i) * 8 + kt) * 64 + l];
            wfz[i][kt] = WH[((6 * wave + 2 + i) * 8 + kt) * 64 + l];
            wfc[i][kt] = WH[((6 * wave + 4 + i) * 8 + kt) * 64 + l];
            PIN_A(wfr[i][kt]); PIN_A(wfz[i][kt]); PIN_A(wfc[i][kt]);
        }
    for (int idx = th; idx < 16 * 264; idx += 512) ((unsigned short*)Hb)[idx] = 0;
    float h[2][4];
    #pragma unroll
    for (int i = 0; i < 2; ++i)
        #pragma unroll
        for (int r = 0; r < 4; ++r) h[i][r] = 0.f;

    const char* Xg = (const char*)ws + X_OFF;
    {   // prime t=0 -> buf 0
        const char* sb = Xg + (((size_t)b) * NTC + 6 * wave) * 512;
        char* db = Xr + wave * 3072;
        #pragma unroll
        for (int inst = 0; inst < 3; ++inst)
            async_ld16(sb + inst * 1024 + l * 16, db + inst * 1024);
    }
    __syncthreads();

    for (int t = 0; t < SEQ; ++t) {
        int buf = t & 1;
        {   // prefetch t+1 -> buf^1 (drained at phase-A barrier)
            int t1 = (t + 1 < SEQ) ? t + 1 : t;
            const char* sb = Xg + (((size_t)(t1 * 16 + b)) * NTC + 6 * wave) * 512;
            char* db = Xr + (buf ^ 1) * 24576 + wave * 3072;
            #pragma unroll
            for (int inst = 0; inst < 3; ++inst)
                async_ld16(sb + inst * 1024 + l * 16, db + inst * 1024);
        }
        const char* Xw = Xr + buf * 24576 + wave * 3072;

        // ---- phase A: r,z preacts; A = h(prev) ----
        f32x4 ar[2], az[2];
        #pragma unroll
        for (int i = 0; i < 2; ++i) {
            ar[i] = cvt4(*(const u32x2*)(Xw + (size_t)i * 512 + l * 8));
            az[i] = cvt4(*(const u32x2*)(Xw + (size_t)(2 + i) * 512 + l * 8));
        }
        #pragma unroll
        for (int kt = 0; kt < 8; ++kt) {
            s16x8 a = *(const s16x8*)&Hb[lan][kt * 32 + qx8];
            #pragma unroll
            for (int i = 0; i < 2; ++i) {
                ar[i] = __builtin_amdgcn_mfma_f32_16x16x32_bf16(a, wfr[i][kt], ar[i], 0, 0, 0);
                az[i] = __builtin_amdgcn_mfma_f32_16x16x32_bf16(a, wfz[i][kt], az[i], 0, 0, 0);
            }
        }
        #pragma unroll
        for (int i = 0; i < 2; ++i) {
            #pragma unroll
            for (int r = 0; r < 4; ++r) {
                float rg = RCPF(1.f + EXP2F(-ar[i][r]));
                RHb[quad * 4 + r][colw[i]] = f2bf_fast(rg * h[i][r]);
            }
        }
        __syncthreads();

        // ---- phase B: candidate; A = r*h; z applied from regs ----
        f32x4 ac[2];
        #pragma unroll
        for (int i = 0; i < 2; ++i)
            ac[i] = cvt4(*(const u32x2*)(Xw + (size_t)(4 + i) * 512 + l * 8));
        #pragma unroll
        for (int kt = 0; kt < 8; ++kt) {
            s16x8 a = *(const s16x8*)&RHb[lan][kt * 32 + qx8];
            #pragma unroll
            for (int i = 0; i < 2; ++i)
                ac[i] = __builtin_amdgcn_mfma_f32_16x16x32_bf16(a, wfc[i][kt], ac[i], 0, 0, 0);
        }
        #pragma unroll
        for (int i = 0; i < 2; ++i) {
            #pragma unroll
            for (int r = 0; r < 4; ++r) {
                float zg = RCPF(1.f + EXP2F(-az[i][r]));
                float e  = EXP2F(ac[i][r]);              // exp(2*preact)
                float hc = (e - 1.f) * RCPF(e + 1.f);    // tanh
                float hn = zg * (h[i][r] - hc) + hc;
                h[i][r] = hn;
                Hb[quad * 4 + r][colw[i]] = f2bf_fast(hn);
            }
        }
        __syncthreads();
    }

    // ---- epilogue: out = h_last @ Wo + bo; wave w owns nt_o {2w, 2w+1} ----
    const s16x8* WO = (const s16x8*)((char*)ws + WO_OFF);
    #pragma unroll
    for (int i = 0; i < 2; ++i) {
        int nt = 2 * wave + i;
        int col = nt * 16 + lan;
        float bv = bo[col];
        f32x4 acc;
        acc[0] = bv; acc[1] = bv; acc[2] = bv; acc[3] = bv;
        #pragma unroll
        for (int kt = 0; kt < 8; ++kt) {
            s16x8 a = *(const s16x8*)&Hb[lan][kt * 32 + qx8];
            acc = __builtin_amdgcn_mfma_f32_16x16x32_bf16(a, WO[(kt * NT_O + nt) * 64 + l], acc, 0, 0, 0);
        }
        #pragma unroll
        for (int r = 0; r < 4; ++r)
            out[(size_t)(b * 16 + quad * 4 + r) * 256 + col] = acc[r];
    }
}

// ---------------- fallbacks (ws too small) ----------------
__global__ __launch_bounds__(256) void prep_weights_k(
    const float* __restrict__ Wr, const float* __restrict__ Wz,
    const float* __restrict__ Wh, unsigned short* __restrict__ W16)
{
    const int n = DTOT * HIDDEN;
    int idx = blockIdx.x * 256 + threadIdx.x;
    if (idx >= 3 * n) return;
    int m = idx / n;
    int r = idx - m * n;
    const float* src = (m == 0) ? Wr : ((m == 1) ? Wz : Wh);
    W16[idx] = f2bf(src[r]);
}
__device__ __forceinline__ float ldw(const unsigned short* p) { return bf2f(*p); }
__device__ __forceinline__ float ldw(const float* p)          { return *p; }

template <typename WT>
__global__ __launch_bounds__(256) void gru_seq_k(
    const float* __restrict__ x,
    const WT* __restrict__ Wr, const WT* __restrict__ Wz, const WT* __restrict__ Wh,
    const float* __restrict__ br, const float* __restrict__ bz, const float* __restrict__ bh,
    const float* __restrict__ Wo, const float* __restrict__ bo,
    float* __restrict__ out)
{
    const int b = blockIdx.x, j = threadIdx.x;
    __shared__ float xh[DTOT];
    __shared__ float xrh[DTOT];
    xh[INPUT + j] = 0.0f;
    const float brj = br[j], bzj = bz[j], bhj = bh[j];
    const float* xb = x + (size_t)b * SEQ * INPUT;
    const WT* wrj = Wr + j;
    const WT* wzj = Wz + j;
    const WT* whj = Wh + j;
    __syncthreads();
    for (int t = 0; t < SEQ; ++t) {
        float xv = xb[t * INPUT + j];
        xh[j] = xv; xrh[j] = xv;
        __syncthreads();
        float ar = brj, az = bzj;
        #pragma unroll 8
        for (int k = 0; k < DTOT; ++k) {
            float v = xh[k];
            ar += v * ldw(wrj + k * HIDDEN);
            az += v * ldw(wzj + k * HIDDEN);
        }
        float rg = 1.0f / (1.0f + __expf(-ar));
        float zg = 1.0f / (1.0f + __expf(-az));
        float hj = xh[INPUT + j];
        xrh[INPUT + j] = rg * hj;
        __syncthreads();
        float ah = bhj;
        #pragma unroll 8
        for (int k = 0; k < DTOT; ++k) ah += xrh[k] * ldw(whj + k * HIDDEN);
        float hc = tanhf(ah);
        float hn = zg * hj + (1.0f - zg) * hc;
        xh[INPUT + j] = hn;
        __syncthreads();
    }
    float acc = bo[j];
    #pragma unroll 8
    for (int k = 0; k < HIDDEN; ++k) acc += xh[INPUT + k] * Wo[k * HIDDEN + j];
    out[(size_t)b * HIDDEN + j] = acc;
}

extern "C" void kernel_launch(void* const* d_in, const int* in_sizes, int n_in,
                              void* d_out, int out_size, void* d_ws, size_t ws_size,
                              hipStream_t stream) {
    const float* x  = (const float*)d_in[0];
    const float* Wr = (const float*)d_in[1];
    const float* br = (const float*)d_in[2];
    const float* Wz = (const float*)d_in[3];
    const float* bz = (const float*)d_in[4];
    const float* Wh = (const float*)d_in[5];
    const float* bh = (const float*)d_in[6];
    const float* Wo = (const float*)d_in[7];
    const float* bo = (const float*)d_in[8];
    float* out = (float*)d_out;

    if (ws_size >= WS_NEED) {
        unsigned short* ws = (unsigned short*)d_ws;
        (void)hipFuncSetAttribute((const void*)gru_rec_k,
                                  hipFuncAttributeMaxDynamicSharedMemorySize, 66048);
        pack_weights_k<<<224, 256, 0, stream>>>(Wr, Wz, Wh, Wo, ws);
        xgemm_k<<<256, 512, 0, stream>>>(x, br, bz, bh, ws);
        gru_rec_k<<<16, 512, 66048, stream>>>(bo, ws, out);
    } else if (ws_size >= WS_NEED_OLD) {
        unsigned short* W16 = (unsigned short*)d_ws;
        const size_t n = (size_t)DTOT * HIDDEN;
        prep_weights_k<<<(int)((3 * n + 255) / 256), 256, 0, stream>>>(Wr, Wz, Wh, W16);
        gru_seq_k<unsigned short><<<BATCH, 256, 0, stream>>>(
            x, W16, W16 + n, W16 + 2 * n, br, bz, bh, Wo, bo, out);
    } else {
        gru_seq_k<float><<<BATCH, 256, 0, stream>>>(
            x, Wr, Wz, Wh, br, bz, bh, Wo, bo, out);
    }
}